// Round 1
// baseline (617.646 us; speedup 1.0000x reference)
//
#include <hip/hip_runtime.h>
#include <cstdint>
#include <cstddef>

typedef _Float16 f16;
typedef _Float16 f16x8 __attribute__((ext_vector_type(8)));
typedef _Float16 f16x4 __attribute__((ext_vector_type(4)));
typedef float    f32x4 __attribute__((ext_vector_type(4)));

typedef const void __attribute__((address_space(1))) gconst_void;
typedef void __attribute__((address_space(3)))       lds_void;

#define LDS_IN_HALF_ELEMS (6*66*40)              // 15840 f16 per half
#define LDS_IN_BYTES      (2*6*66*40*2)          // 63360 B
#define WBUF_BYTES        32768                  // one (ck,tap) weight tile
#define SMEM_TOTAL        (LDS_IN_BYTES + 2*WBUF_BYTES)  // 128896 B
#define WF_BYTES          37748736ULL            // 16*9*8*16*2*64*8 f16 * 2B

__device__ __forceinline__ int lin_idx(int half, int row, int col, int ci) {
    return ((half*6 + row)*66 + col)*40 + ci;    // f16 element index, pad-40 cin stride
}

__device__ __forceinline__ void gll16(const char* g, char* l) {
    __builtin_amdgcn_global_load_lds((gconst_void*)g, (lds_void*)l, 16, 0, 0);
}

// ---------------------------------------------------------------------------
// prep: style GEMV + modulate + demod + x64 scale + f16 hi/lo split,
// written in MFMA-A-fragment-swizzled layout:
// wf[b][tap][ck][cg][half][lane][j]  (lane = (cout&15) + 16*((cin>>3)&3), j = cin&7)
// ---------------------------------------------------------------------------
__global__ __launch_bounds__(256) void prep_kernel(
    const float* __restrict__ style_vec,  // [16,512]
    const float* __restrict__ s_w,        // [256,512]
    const float* __restrict__ s_b,        // [256]
    const float* __restrict__ conv_w,     // [256,256,3,3]
    f16* __restrict__ wf)
{
    const int b = blockIdx.x & 15;
    const int g = blockIdx.x >> 4;        // 0..7 : cout group of 32
    const int t = threadIdx.x;
    __shared__ float style[256];
    {
        const float4* sv = (const float4*)(style_vec + b*512);
        const float4* sw = (const float4*)(s_w + (size_t)t*512);
        float acc = 0.f;
        for (int i = 0; i < 128; ++i) {
            float4 a = sv[i], w = sw[i];
            acc += a.x*w.x + a.y*w.y + a.z*w.z + a.w*w.w;
        }
        style[t] = acc * 0.03125f + s_b[t];   // scale = 2^-.5 * 512^-.5 = 1/32
    }
    __syncthreads();

    const int cout = g*32 + (t >> 3);
    const int sub  = t & 7;               // = cin chunk (ck) this thread owns
    const int cin0 = sub * 32;
    const float* wrow = conv_w + (size_t)cout * 2304;

    float ss = 0.f;
    for (int ci = 0; ci < 32; ++ci) {
        float st = style[cin0 + ci];
        const float* wp = wrow + (cin0 + ci)*9;
        #pragma unroll
        for (int kk = 0; kk < 9; ++kk) { float v = wp[kk]*st; ss += v*v; }
    }
    ss += __shfl_xor(ss, 1);
    ss += __shfl_xor(ss, 2);
    ss += __shfl_xor(ss, 4);
    const float dem = 64.f / sqrtf(ss + 1e-8f);   // demod * 2^6 denormal-guard scale

    const int cg = cout >> 4;
    const int lane_lo = cout & 15;
    for (int kg = 0; kg < 4; ++kg) {
        float stv[8];
        #pragma unroll
        for (int j = 0; j < 8; ++j) stv[j] = style[cin0 + kg*8 + j] * dem;
        for (int kk = 0; kk < 9; ++kk) {
            f16x8 hi, lo;
            #pragma unroll
            for (int j = 0; j < 8; ++j) {
                float v = wrow[(cin0 + kg*8 + j)*9 + kk] * stv[j];
                f16 h = (f16)v;
                hi[j] = h;
                lo[j] = (f16)(v - (float)h);
            }
            size_t base = ((((size_t)(b*9 + kk)*8 + sub)*16 + cg)*2)*512
                        + (size_t)(lane_lo + 16*kg)*8;
            *(f16x8*)(wf + base)       = hi;
            *(f16x8*)(wf + base + 512) = lo;
        }
    }
}

// ---------------------------------------------------------------------------
// conv: implicit GEMM, block = 256 Cout x 4 rows, 8 waves (wave = 128 Cout x 64 px)
// MODE 0: fp32 input (x), writes h as interleaved f16 (hi,lo) pairs
// MODE 1: pair input (h), writes fp32 output
// ---------------------------------------------------------------------------
template<int MODE>
__global__ __launch_bounds__(512, 2) void conv_kernel(
    const float*    __restrict__ in32,
    const uint32_t* __restrict__ in_pair,
    const f16*      __restrict__ wf,
    const float*    __restrict__ noise,   // [16,4096]
    const float*    __restrict__ nw,      // [256]
    float*          __restrict__ out32,
    uint32_t*       __restrict__ out_pair)
{
    extern __shared__ __align__(16) char smem[];
    f16*  lds_in = (f16*)smem;
    char* wbuf   = smem + LDS_IN_BYTES;

    const int tid  = threadIdx.x;
    const int b    = blockIdx.x & 15;          // batch in low bits -> same XCD per batch
    const int y0   = (blockIdx.x >> 4) * 4;
    const int lane = tid & 63;
    const int wave = tid >> 6;
    const int wm   = wave & 1;                 // cout half (0/1 -> 128 couts)
    const int wn   = wave >> 1;                // row within 4-row tile
    const int lcol = lane & 15;
    const int kg   = lane >> 4;

    // zero the SAME-padding columns (col 0 and 65) once
    for (int e = tid; e < 2*6*2*40; e += 512) {
        int half = e / 480; int rem = e - half*480;
        int row = rem / 80; int rem2 = rem - row*80;
        int side = rem2 / 40; int ci = rem2 - side*40;
        lds_in[lin_idx(half, row, side ? 65 : 0, ci)] = (f16)0.f;
    }

    f32x4 acc[8][4];
    #pragma unroll
    for (int m = 0; m < 8; ++m)
        #pragma unroll
        for (int n = 0; n < 4; ++n)
            acc[m][n] = (f32x4){0.f, 0.f, 0.f, 0.f};

    const int y = y0 + wn;
    float nz[4];
    #pragma unroll
    for (int n = 0; n < 4; ++n) nz[n] = noise[b*4096 + y*64 + n*16 + lcol];

    const char* wf_b = (const char*)wf + (size_t)b * 9 * 8 * WBUF_BYTES;

    #pragma unroll 1
    for (int ck = 0; ck < 8; ++ck) {
        __syncthreads();   // lds_in free to overwrite (prev chunk fully consumed)

        // ---- stage input chunk: rows y0-1..y0+4, 64 cols, 32 cin, hi/lo f16 ----
        #pragma unroll
        for (int i = 0; i < 6; ++i) {
            int grp = i*512 + tid;
            int col, row, ci0;
            if (MODE == 0) { col = grp & 63; row = (grp >> 6) % 6; ci0 = (grp / 384) * 4; }
            else           { ci0 = (grp & 7) * 4; col = (grp >> 3) & 63; row = grp >> 9; }
            int gy = y0 - 1 + row;
            f16x4 hi4 = (f16x4){(f16)0.f,(f16)0.f,(f16)0.f,(f16)0.f};
            f16x4 lo4 = hi4;
            if (gy >= 0 && gy < 64) {
                if (MODE == 0) {
                    const float* p = in32 + ((size_t)(b*256 + ck*32 + ci0))*4096 + gy*64 + col;
                    #pragma unroll
                    for (int k = 0; k < 4; ++k) {
                        float xv = p[(size_t)k*4096] * 64.f;   // 2^6 denormal guard
                        f16 h = (f16)xv;
                        hi4[k] = h;
                        lo4[k] = (f16)(xv - (float)h);
                    }
                } else {
                    const f16x8 pr = *(const f16x8*)(in_pair +
                        ((size_t)((b*8 + ck)*64 + gy)*64 + col)*32 + ci0);
                    hi4 = __builtin_shufflevector(pr, pr, 0, 2, 4, 6);
                    lo4 = __builtin_shufflevector(pr, pr, 1, 3, 5, 7);
                }
            }
            *(f16x4*)(lds_in + lin_idx(0, row, col + 1, ci0)) = hi4;
            *(f16x4*)(lds_in + lin_idx(1, row, col + 1, ci0)) = lo4;
        }

        // prefetch weights for tap 0 into buffer 0
        {
            const char* gsw = wf_b + (size_t)(0*8 + ck) * WBUF_BYTES;
            char* lsw = wbuf;
            #pragma unroll
            for (int r = 0; r < 4; ++r) {
                int off = (r*512 + tid) * 16;
                gll16(gsw + off, lsw + off);
            }
        }

        #pragma unroll 1
        for (int t = 0; t < 9; ++t) {
            __syncthreads();   // weights(t) landed (vmcnt drained), buffers safe
            if (t < 8) {       // async prefetch next tap's weights
                const char* gsw = wf_b + (size_t)((t+1)*8 + ck) * WBUF_BYTES;
                char* lsw = wbuf + ((t+1)&1) * WBUF_BYTES;
                #pragma unroll
                for (int r = 0; r < 4; ++r) {
                    int off = (r*512 + tid) * 16;
                    gll16(gsw + off, lsw + off);
                }
            }
            const int kh = t / 3, kw = t - kh*3;
            const f16* wcur = (const f16*)(wbuf + (t&1) * WBUF_BYTES);

            f16x8 bhi[4], blo[4];
            #pragma unroll
            for (int n = 0; n < 4; ++n) {
                int e = ((wn + kh)*66 + n*16 + lcol + kw)*40 + kg*8;
                bhi[n] = *(const f16x8*)(lds_in + e);
                blo[n] = *(const f16x8*)(lds_in + e + LDS_IN_HALF_ELEMS);
            }
            #pragma unroll
            for (int m = 0; m < 8; ++m) {
                const f16* ap = wcur + (size_t)((wm*8 + m)*2)*512 + lane*8;
                f16x8 ahi = *(const f16x8*)ap;
                f16x8 alo = *(const f16x8*)(ap + 512);
                #pragma unroll
                for (int n = 0; n < 4; ++n) {
                    acc[m][n] = __builtin_amdgcn_mfma_f32_16x16x32_f16(ahi, bhi[n], acc[m][n], 0, 0, 0);
                    acc[m][n] = __builtin_amdgcn_mfma_f32_16x16x32_f16(ahi, blo[n], acc[m][n], 0, 0, 0);
                    acc[m][n] = __builtin_amdgcn_mfma_f32_16x16x32_f16(alo, bhi[n], acc[m][n], 0, 0, 0);
                }
            }
        }
    }

    // ---- epilogue: /4096 (input&weight 2^6 scales), +noise, leaky 0.2 ----
    const float inv = 1.f / 4096.f;
    #pragma unroll
    for (int m = 0; m < 8; ++m) {
        const int coutb = wm*128 + m*16 + kg*4;
        float nwv[4];
        #pragma unroll
        for (int r = 0; r < 4; ++r) nwv[r] = nw[coutb + r];
        #pragma unroll
        for (int n = 0; n < 4; ++n) {
            const int col = n*16 + lcol;
            #pragma unroll
            for (int r = 0; r < 4; ++r) {
                float v = acc[m][n][r]*inv + nwv[r]*nz[n];
                v = fmaxf(v, 0.2f*v);                 // leaky relu 0.2
                const int cout = coutb + r;
                if (MODE == 0) {
                    float vs = v * 64.f;
                    f16 h = (f16)vs;
                    f16 l = (f16)(vs - (float)h);
                    uint32_t pk = (uint32_t)__builtin_bit_cast(uint16_t, h)
                                | ((uint32_t)__builtin_bit_cast(uint16_t, l) << 16);
                    size_t idx = (((size_t)(b*8 + (cout >> 5))*64 + y)*64 + col)*32 + (cout & 31);
                    out_pair[idx] = pk;
                } else {
                    out32[((size_t)(b*256 + cout))*4096 + y*64 + col] = v;
                }
            }
        }
    }
}

// ---------------------------------------------------------------------------
extern "C" void kernel_launch(void* const* d_in, const int* in_sizes, int n_in,
                              void* d_out, int out_size, void* d_ws, size_t ws_size,
                              hipStream_t stream) {
    (void)in_sizes; (void)n_in; (void)out_size; (void)ws_size;
    const float* x      = (const float*)d_in[0];
    const float* w1     = (const float*)d_in[1];
    const float* w2     = (const float*)d_in[2];
    const float* noise1 = (const float*)d_in[3];
    const float* noise2 = (const float*)d_in[4];
    const float* s1w    = (const float*)d_in[5];
    const float* s1b    = (const float*)d_in[6];
    const float* c1w    = (const float*)d_in[7];
    const float* nw1    = (const float*)d_in[8];
    const float* s2w    = (const float*)d_in[9];
    const float* s2b    = (const float*)d_in[10];
    const float* c2w    = (const float*)d_in[11];
    const float* nw2    = (const float*)d_in[12];
    float* out = (float*)d_out;

    f16*      wf    = (f16*)d_ws;
    uint32_t* hpair = (uint32_t*)((char*)d_ws + WF_BYTES);   // 16*8*64*64*32 u32 = 67.1MB

    (void)hipFuncSetAttribute(reinterpret_cast<const void*>(&conv_kernel<0>),
                              hipFuncAttributeMaxDynamicSharedMemorySize, SMEM_TOTAL);
    (void)hipFuncSetAttribute(reinterpret_cast<const void*>(&conv_kernel<1>),
                              hipFuncAttributeMaxDynamicSharedMemorySize, SMEM_TOTAL);

    prep_kernel<<<128, 256, 0, stream>>>(w1, s1w, s1b, c1w, wf);
    conv_kernel<0><<<256, 512, SMEM_TOTAL, stream>>>(x, nullptr, wf, noise1, nw1, nullptr, hpair);
    prep_kernel<<<128, 256, 0, stream>>>(w2, s2w, s2b, c2w, wf);
    conv_kernel<1><<<256, 512, SMEM_TOTAL, stream>>>(nullptr, hpair, wf, noise2, nw2, out, nullptr);
}

// Round 4
// 535.111 us; speedup vs baseline: 1.1542x; 1.1542x over previous
//
#include <hip/hip_runtime.h>
#include <cstdint>
#include <cstddef>

typedef _Float16 f16;
typedef _Float16 f16x8 __attribute__((ext_vector_type(8)));
typedef _Float16 f16x4 __attribute__((ext_vector_type(4)));
typedef float    f32x4 __attribute__((ext_vector_type(4)));

typedef const void __attribute__((address_space(1))) gconst_void;
typedef void __attribute__((address_space(3)))       lds_void;

#define LDS_IN_HALF_ELEMS (6*66*40)              // 15840 f16 per half (hi/lo of input)
#define LDS_IN_BYTES      (2*6*66*40*2)          // 63360 B
#define WTILE_BYTES       8192                   // one (tap,ck,couthalf) weight tile: 128cout x 32cin f16
#define SMEM_TOTAL        (LDS_IN_BYTES + 2*WTILE_BYTES)   // 79744 B -> 2 blocks/CU
#define WF_BYTES          (16ULL*144*8192)       // 18,874,368 B (single-f16 weights)

__device__ __forceinline__ int lin_idx(int half, int row, int col, int ci) {
    return ((half*6 + row)*66 + col)*40 + ci;    // f16 element index, pad-40 cin stride
}

__device__ __forceinline__ void gll16(const char* g, char* l) {
    __builtin_amdgcn_global_load_lds((gconst_void*)g, (lds_void*)l, 16, 0, 0);
}

// ---------------------------------------------------------------------------
// prep: style GEMV + modulate + demod + x64 scale, SINGLE f16 weights,
// MFMA-A-fragment layout per tile (8KB):
//   tile = ((b*9+kk)*8+ck)*2 + ch ;  within tile: [m][lane][j]
//   lane = (cout&15) + 16*((cin>>3)&3), j = cin&7, m = (cout>>4)&7
// ---------------------------------------------------------------------------
__global__ __launch_bounds__(256) void prep_kernel(
    const float* __restrict__ style_vec,  // [16,512]
    const float* __restrict__ s_w,        // [256,512]
    const float* __restrict__ s_b,        // [256]
    const float* __restrict__ conv_w,     // [256,256,3,3]
    f16* __restrict__ wf)
{
    const int b = blockIdx.x & 15;
    const int g = blockIdx.x >> 4;        // 0..7 : cout group of 32
    const int t = threadIdx.x;
    __shared__ float style[256];
    {
        const float4* sv = (const float4*)(style_vec + b*512);
        const float4* sw = (const float4*)(s_w + (size_t)t*512);
        float acc = 0.f;
        for (int i = 0; i < 128; ++i) {
            float4 a = sv[i], w = sw[i];
            acc += a.x*w.x + a.y*w.y + a.z*w.z + a.w*w.w;
        }
        style[t] = acc * 0.03125f + s_b[t];   // scale = 2^-.5 * 512^-.5 = 1/32
    }
    __syncthreads();

    const int cout = g*32 + (t >> 3);
    const int sub  = t & 7;               // = cin chunk (ck) this thread owns
    const int cin0 = sub * 32;
    const float* wrow = conv_w + (size_t)cout * 2304;

    float ss = 0.f;
    for (int ci = 0; ci < 32; ++ci) {
        float st = style[cin0 + ci];
        const float* wp = wrow + (cin0 + ci)*9;
        #pragma unroll
        for (int kk = 0; kk < 9; ++kk) { float v = wp[kk]*st; ss += v*v; }
    }
    ss += __shfl_xor(ss, 1);
    ss += __shfl_xor(ss, 2);
    ss += __shfl_xor(ss, 4);
    const float dem = 64.f / sqrtf(ss + 1e-8f);   // demod * 2^6 range-guard scale

    const int ch = cout >> 7;
    const int m  = (cout >> 4) & 7;
    const int lane_lo = cout & 15;
    const size_t bch_base = ((size_t)b*144 + ch) * 4096;   // f16 elems (tile = 4096 f16)

    for (int kg = 0; kg < 4; ++kg) {
        float stv[8];
        #pragma unroll
        for (int j = 0; j < 8; ++j) stv[j] = style[cin0 + kg*8 + j] * dem;
        for (int kk = 0; kk < 9; ++kk) {
            f16x8 hi;
            #pragma unroll
            for (int j = 0; j < 8; ++j)
                hi[j] = (f16)(wrow[(cin0 + kg*8 + j)*9 + kk] * stv[j]);
            size_t off = bch_base + (size_t)((kk*8 + sub)*2) * 4096
                       + (size_t)(m*64 + lane_lo + 16*kg) * 8;
            *(f16x8*)(wf + off) = hi;
        }
    }
}

// ---------------------------------------------------------------------------
// conv: implicit GEMM. block = 256 threads (4 waves) = 128 cout (half ch) x 4 rows.
// wave = 128 cout x 64 px, acc[8][4]. 2 blocks/CU.
// 2-pass MFMA: w_f16 x x_hi + w_f16 x x_lo.
// MODE 0: fp32 input (x), writes h as interleaved f16 (hi,lo) pairs
// MODE 1: pair input (h), writes fp32 output
// ---------------------------------------------------------------------------
template<int MODE>
__global__ __launch_bounds__(256, 2) void conv_kernel(
    const float*    __restrict__ in32,
    const uint32_t* __restrict__ in_pair,
    const f16*      __restrict__ wf,
    const float*    __restrict__ noise,   // [16,4096]
    const float*    __restrict__ nw,      // [256]
    float*          __restrict__ out32,
    uint32_t*       __restrict__ out_pair)
{
    extern __shared__ __align__(16) char smem[];
    f16*  lds_in = (f16*)smem;
    char* wbuf   = smem + LDS_IN_BYTES;

    const int tid  = threadIdx.x;
    const int bid  = blockIdx.x;
    const int b    = bid & 15;                 // all 32 blocks of a batch -> same XCD
    const int y0   = ((bid >> 4) & 15) * 4;
    const int ch   = bid >> 8;                 // cout half
    const int lane = tid & 63;
    const int wn   = tid >> 6;                 // wave = row within 4-row tile
    const int lcol = lane & 15;
    const int kg   = lane >> 4;

    const char* wf_bch = (const char*)wf + ((size_t)b*144 + ch) * WTILE_BYTES;

    auto stage_w = [&](int ck_, int t_, int buf_) {
        const char* gsw = wf_bch + (size_t)((t_*8 + ck_)*2) * WTILE_BYTES;
        char* lsw = wbuf + buf_ * WTILE_BYTES;
        gll16(gsw + tid*16, lsw + tid*16);
        gll16(gsw + 4096 + tid*16, lsw + 4096 + tid*16);
    };

    stage_w(0, 0, 0);   // prefetch weights for global tap T=0

    // zero the SAME-padding columns (col 0 and 65), both hi/lo halves, once
    for (int e = tid; e < 2*6*2*40; e += 256) {
        int half = e / 480; int rem = e - half*480;
        int row = rem / 80; int rem2 = rem - row*80;
        int side = rem2 / 40; int ci = rem2 - side*40;
        lds_in[lin_idx(half, row, side ? 65 : 0, ci)] = (f16)0.f;
    }

    f32x4 acc[8][4];
    #pragma unroll
    for (int m = 0; m < 8; ++m)
        #pragma unroll
        for (int n = 0; n < 4; ++n)
            acc[m][n] = (f32x4){0.f, 0.f, 0.f, 0.f};

    const int y = y0 + wn;
    float nz[4];
    #pragma unroll
    for (int n = 0; n < 4; ++n) nz[n] = noise[b*4096 + y*64 + n*16 + lcol];

    #pragma unroll 1
    for (int ck = 0; ck < 8; ++ck) {
        __syncthreads();   // A: prev chunk fully consumed; lds_in reusable

        // ---- stage input chunk: rows y0-1..y0+4, 64 cols, 32 cin, hi/lo f16 ----
        #pragma unroll 3
        for (int i = 0; i < 12; ++i) {
            int grp = i*256 + tid;
            int col, row, ci0;
            if (MODE == 0) { col = grp & 63; row = (grp >> 6) % 6; ci0 = (grp / 384) * 4; }
            else           { ci0 = (grp & 7) * 4; col = (grp >> 3) & 63; row = grp >> 9; }
            int gy = y0 - 1 + row;
            f16x4 hi4 = (f16x4){(f16)0.f,(f16)0.f,(f16)0.f,(f16)0.f};
            f16x4 lo4 = hi4;
            if (gy >= 0 && gy < 64) {
                if (MODE == 0) {
                    const float* p = in32 + ((size_t)(b*256 + ck*32 + ci0))*4096 + gy*64 + col;
                    #pragma unroll
                    for (int k = 0; k < 4; ++k) {
                        float xv = p[(size_t)k*4096] * 64.f;   // 2^6 range guard
                        f16 h = (f16)xv;
                        hi4[k] = h;
                        lo4[k] = (f16)(xv - (float)h);
                    }
                } else {
                    const f16x8 pr = *(const f16x8*)(in_pair +
                        ((size_t)((b*8 + ck)*64 + gy)*64 + col)*32 + ci0);
                    hi4 = __builtin_shufflevector(pr, pr, 0, 2, 4, 6);
                    lo4 = __builtin_shufflevector(pr, pr, 1, 3, 5, 7);
                }
            }
            *(f16x4*)(lds_in + lin_idx(0, row, col + 1, ci0)) = hi4;
            *(f16x4*)(lds_in + lin_idx(1, row, col + 1, ci0)) = lo4;
        }

        __syncthreads();   // B: staging + this chunk's first weight tile visible

        #pragma unroll
        for (int t = 0; t < 9; ++t) {
            if (t) __syncthreads();   // weights(T) landed; other buf free to overwrite
            // issue next tap's weight prefetch (lands before next barrier)
            if (t < 8)        stage_w(ck, t+1, (ck + t + 1) & 1);
            else if (ck < 7)  stage_w(ck+1, 0, (ck + 1) & 1);

            const int kh = t / 3, kw = t - kh*3;
            const f16* wcur = (const f16*)(wbuf + ((ck + t) & 1) * WTILE_BYTES);

            f16x8 bhi[4], blo[4];
            #pragma unroll
            for (int n = 0; n < 4; ++n) {
                int e = ((wn + kh)*66 + n*16 + lcol + kw)*40 + kg*8;
                bhi[n] = *(const f16x8*)(lds_in + e);
                blo[n] = *(const f16x8*)(lds_in + e + LDS_IN_HALF_ELEMS);
            }
            __builtin_amdgcn_s_setprio(1);
            #pragma unroll
            for (int m = 0; m < 8; ++m) {
                f16x8 a = *(const f16x8*)(wcur + m*512 + lane*8);
                #pragma unroll
                for (int n = 0; n < 4; ++n) {
                    acc[m][n] = __builtin_amdgcn_mfma_f32_16x16x32_f16(a, bhi[n], acc[m][n], 0, 0, 0);
                    acc[m][n] = __builtin_amdgcn_mfma_f32_16x16x32_f16(a, blo[n], acc[m][n], 0, 0, 0);
                }
            }
            __builtin_amdgcn_s_setprio(0);
        }
    }

    // ---- epilogue: /4096 (input&weight 2^6 scales), +noise, leaky 0.2 ----
    const float inv = 1.f / 4096.f;
    #pragma unroll
    for (int m = 0; m < 8; ++m) {
        const int coutb = ch*128 + m*16 + kg*4;
        float nwv[4];
        #pragma unroll
        for (int r = 0; r < 4; ++r) nwv[r] = nw[coutb + r];
        #pragma unroll
        for (int n = 0; n < 4; ++n) {
            const int col = n*16 + lcol;
            #pragma unroll
            for (int r = 0; r < 4; ++r) {
                float v = acc[m][n][r]*inv + nwv[r]*nz[n];
                v = fmaxf(v, 0.2f*v);                 // leaky relu 0.2
                const int cout = coutb + r;
                if (MODE == 0) {
                    float vs = v * 64.f;
                    f16 h = (f16)vs;
                    f16 l = (f16)(vs - (float)h);
                    uint32_t pk = (uint32_t)__builtin_bit_cast(uint16_t, h)
                                | ((uint32_t)__builtin_bit_cast(uint16_t, l) << 16);
                    size_t idx = (((size_t)(b*8 + (cout >> 5))*64 + y)*64 + col)*32 + (cout & 31);
                    out_pair[idx] = pk;
                } else {
                    out32[((size_t)(b*256 + cout))*4096 + y*64 + col] = v;
                }
            }
        }
    }
}

// ---------------------------------------------------------------------------
extern "C" void kernel_launch(void* const* d_in, const int* in_sizes, int n_in,
                              void* d_out, int out_size, void* d_ws, size_t ws_size,
                              hipStream_t stream) {
    (void)in_sizes; (void)n_in; (void)out_size; (void)ws_size;
    const float* x      = (const float*)d_in[0];
    const float* w1     = (const float*)d_in[1];
    const float* w2     = (const float*)d_in[2];
    const float* noise1 = (const float*)d_in[3];
    const float* noise2 = (const float*)d_in[4];
    const float* s1w    = (const float*)d_in[5];
    const float* s1b    = (const float*)d_in[6];
    const float* c1w    = (const float*)d_in[7];
    const float* nw1    = (const float*)d_in[8];
    const float* s2w    = (const float*)d_in[9];
    const float* s2b    = (const float*)d_in[10];
    const float* c2w    = (const float*)d_in[11];
    const float* nw2    = (const float*)d_in[12];
    float* out = (float*)d_out;

    f16*      wf    = (f16*)d_ws;
    uint32_t* hpair = (uint32_t*)((char*)d_ws + WF_BYTES);   // 16*8*64*64*32 u32 = 67.1MB

    (void)hipFuncSetAttribute(reinterpret_cast<const void*>(&conv_kernel<0>),
                              hipFuncAttributeMaxDynamicSharedMemorySize, SMEM_TOTAL);
    (void)hipFuncSetAttribute(reinterpret_cast<const void*>(&conv_kernel<1>),
                              hipFuncAttributeMaxDynamicSharedMemorySize, SMEM_TOTAL);

    prep_kernel<<<128, 256, 0, stream>>>(w1, s1w, s1b, c1w, wf);
    conv_kernel<0><<<512, 256, SMEM_TOTAL, stream>>>(x, nullptr, wf, noise1, nw1, nullptr, hpair);
    prep_kernel<<<128, 256, 0, stream>>>(w2, s2w, s2b, c2w, wf);
    conv_kernel<1><<<512, 256, SMEM_TOTAL, stream>>>(nullptr, hpair, wf, noise2, nw2, out, nullptr);
}

// Round 5
// 509.917 us; speedup vs baseline: 1.2113x; 1.0494x over previous
//
#include <hip/hip_runtime.h>
#include <cstdint>
#include <cstddef>

typedef _Float16 f16;
typedef _Float16 f16x8 __attribute__((ext_vector_type(8)));
typedef _Float16 f16x4 __attribute__((ext_vector_type(4)));
typedef float    f32x4 __attribute__((ext_vector_type(4)));

#define LDS_IN_HALF_ELEMS (6*66*40)              // 15840 f16 per half (hi/lo of input)
#define LDS_IN_BYTES      (2*6*66*40*2)          // 63360 B  (input only; no weight LDS)
#define SMEM_TOTAL        LDS_IN_BYTES
#define WF_BYTES          (16ULL*144*8192)       // 18,874,368 B (single-f16 weights)

__device__ __forceinline__ int lin_idx(int half, int row, int col, int ci) {
    return ((half*6 + row)*66 + col)*40 + ci;    // f16 element index, pad-40 cin stride
}

// ---------------------------------------------------------------------------
// prep: style GEMV + modulate + demod + x64 scale, SINGLE f16 weights,
// MFMA-A-fragment layout per tile (8KB = 4096 f16):
//   tile = ((b*9+kk)*8+ck)*2 + ch ;  within tile: [m][lane][j]
//   lane = (cout&15) + 16*((cin>>3)&3), j = cin&7, m = (cout>>4)&7
// (UNCHANGED from R2 — conv now reads fragments directly from global.)
// ---------------------------------------------------------------------------
__global__ __launch_bounds__(256) void prep_kernel(
    const float* __restrict__ style_vec,  // [16,512]
    const float* __restrict__ s_w,        // [256,512]
    const float* __restrict__ s_b,        // [256]
    const float* __restrict__ conv_w,     // [256,256,3,3]
    f16* __restrict__ wf)
{
    const int b = blockIdx.x & 15;
    const int g = blockIdx.x >> 4;        // 0..7 : cout group of 32
    const int t = threadIdx.x;
    __shared__ float style[256];
    {
        const float4* sv = (const float4*)(style_vec + b*512);
        const float4* sw = (const float4*)(s_w + (size_t)t*512);
        float acc = 0.f;
        for (int i = 0; i < 128; ++i) {
            float4 a = sv[i], w = sw[i];
            acc += a.x*w.x + a.y*w.y + a.z*w.z + a.w*w.w;
        }
        style[t] = acc * 0.03125f + s_b[t];   // scale = 2^-.5 * 512^-.5 = 1/32
    }
    __syncthreads();

    const int cout = g*32 + (t >> 3);
    const int sub  = t & 7;               // = cin chunk (ck) this thread owns
    const int cin0 = sub * 32;
    const float* wrow = conv_w + (size_t)cout * 2304;

    float ss = 0.f;
    for (int ci = 0; ci < 32; ++ci) {
        float st = style[cin0 + ci];
        const float* wp = wrow + (cin0 + ci)*9;
        #pragma unroll
        for (int kk = 0; kk < 9; ++kk) { float v = wp[kk]*st; ss += v*v; }
    }
    ss += __shfl_xor(ss, 1);
    ss += __shfl_xor(ss, 2);
    ss += __shfl_xor(ss, 4);
    const float dem = 64.f / sqrtf(ss + 1e-8f);   // demod * 2^6 range-guard scale

    const int ch = cout >> 7;
    const int m  = (cout >> 4) & 7;
    const int lane_lo = cout & 15;
    const size_t bch_base = ((size_t)b*144 + ch) * 4096;   // f16 elems (tile = 4096 f16)

    for (int kg = 0; kg < 4; ++kg) {
        float stv[8];
        #pragma unroll
        for (int j = 0; j < 8; ++j) stv[j] = style[cin0 + kg*8 + j] * dem;
        for (int kk = 0; kk < 9; ++kk) {
            f16x8 hi;
            #pragma unroll
            for (int j = 0; j < 8; ++j)
                hi[j] = (f16)(wrow[(cin0 + kg*8 + j)*9 + kk] * stv[j]);
            size_t off = bch_base + (size_t)((kk*8 + sub)*2) * 4096
                       + (size_t)(m*64 + lane_lo + 16*kg) * 8;
            *(f16x8*)(wf + off) = hi;
        }
    }
}

// ---------------------------------------------------------------------------
// conv: implicit GEMM. block = 256 threads (4 waves) = 128 cout (half ch) x 4 rows.
// wave = 128 cout x 64 px, acc[8][4]. 2 blocks/CU (LDS 63,360 B, <=256 VGPR).
// Weights: A-fragments loaded per-lane DIRECTLY from global (L2-resident) ->
// no weight LDS, no per-tap barriers. Only 2 barriers per cin-chunk.
// 2-pass MFMA: w_f16 x x_hi + w_f16 x x_lo.
// MODE 0: fp32 input (x), writes h as interleaved f16 (hi,lo) pairs
// MODE 1: pair input (h), writes fp32 output
// ---------------------------------------------------------------------------
template<int MODE>
__global__ __launch_bounds__(256, 2) void conv_kernel(
    const float*    __restrict__ in32,
    const uint32_t* __restrict__ in_pair,
    const f16*      __restrict__ wf,
    const float*    __restrict__ noise,   // [16,4096]
    const float*    __restrict__ nw,      // [256]
    float*          __restrict__ out32,
    uint32_t*       __restrict__ out_pair)
{
    extern __shared__ __align__(16) char smem[];
    f16* lds_in = (f16*)smem;

    const int tid  = threadIdx.x;
    const int bid  = blockIdx.x;
    const int b    = bid & 15;                 // all 32 blocks of a batch -> same XCD
    const int y0   = ((bid >> 4) & 15) * 4;
    const int ch   = bid >> 8;                 // cout half
    const int lane = tid & 63;
    const int wn   = tid >> 6;                 // wave = row within 4-row tile
    const int lcol = lane & 15;
    const int kg   = lane >> 4;

    const f16* wf_bch = wf + ((size_t)b*144 + ch) * 4096;   // f16 elems; tile = 4096 f16

    // zero the SAME-padding columns (col 0 and 65), both hi/lo halves, once
    for (int e = tid; e < 2*6*2*40; e += 256) {
        int half = e / 480; int rem = e - half*480;
        int row = rem / 80; int rem2 = rem - row*80;
        int side = rem2 / 40; int ci = rem2 - side*40;
        lds_in[lin_idx(half, row, side ? 65 : 0, ci)] = (f16)0.f;
    }

    f32x4 acc[8][4];
    #pragma unroll
    for (int m = 0; m < 8; ++m)
        #pragma unroll
        for (int n = 0; n < 4; ++n)
            acc[m][n] = (f32x4){0.f, 0.f, 0.f, 0.f};

    const int y = y0 + wn;
    float nz[4];
    #pragma unroll
    for (int n = 0; n < 4; ++n) nz[n] = noise[b*4096 + y*64 + n*16 + lcol];

    #pragma unroll 1
    for (int ck = 0; ck < 8; ++ck) {
        __syncthreads();   // A: prev chunk fully consumed; lds_in reusable

        // ---- stage input chunk: rows y0-1..y0+4, 64 cols, 32 cin, hi/lo f16 ----
        #pragma unroll 3
        for (int i = 0; i < 12; ++i) {
            int grp = i*256 + tid;
            int col, row, ci0;
            if (MODE == 0) { col = grp & 63; row = (grp >> 6) % 6; ci0 = (grp / 384) * 4; }
            else           { ci0 = (grp & 7) * 4; col = (grp >> 3) & 63; row = grp >> 9; }
            int gy = y0 - 1 + row;
            f16x4 hi4 = (f16x4){(f16)0.f,(f16)0.f,(f16)0.f,(f16)0.f};
            f16x4 lo4 = hi4;
            if (gy >= 0 && gy < 64) {
                if (MODE == 0) {
                    const float* p = in32 + ((size_t)(b*256 + ck*32 + ci0))*4096 + gy*64 + col;
                    #pragma unroll
                    for (int k = 0; k < 4; ++k) {
                        float xv = p[(size_t)k*4096] * 64.f;   // 2^6 range guard
                        f16 h = (f16)xv;
                        hi4[k] = h;
                        lo4[k] = (f16)(xv - (float)h);
                    }
                } else {
                    const f16x8 pr = *(const f16x8*)(in_pair +
                        ((size_t)((b*8 + ck)*64 + gy)*64 + col)*32 + ci0);
                    hi4 = __builtin_shufflevector(pr, pr, 0, 2, 4, 6);
                    lo4 = __builtin_shufflevector(pr, pr, 1, 3, 5, 7);
                }
            }
            *(f16x4*)(lds_in + lin_idx(0, row, col + 1, ci0)) = hi4;
            *(f16x4*)(lds_in + lin_idx(1, row, col + 1, ci0)) = lo4;
        }

        __syncthreads();   // B: staging visible; taps below are barrier-free

        #pragma unroll
        for (int t = 0; t < 9; ++t) {
            const int kh = t / 3, kw = t - kh*3;

            // A-fragments: per-lane direct global load (coalesced 1KB per m, L2-hot)
            const f16* wt = wf_bch + (size_t)((t*8 + ck)*2) * 4096 + lane*8;
            f16x8 a[8];
            #pragma unroll
            for (int m = 0; m < 8; ++m) a[m] = *(const f16x8*)(wt + m*512);

            f16x8 bhi[4], blo[4];
            #pragma unroll
            for (int n = 0; n < 4; ++n) {
                int e = ((wn + kh)*66 + n*16 + lcol + kw)*40 + kg*8;
                bhi[n] = *(const f16x8*)(lds_in + e);
                blo[n] = *(const f16x8*)(lds_in + e + LDS_IN_HALF_ELEMS);
            }

            __builtin_amdgcn_s_setprio(1);
            #pragma unroll
            for (int m = 0; m < 8; ++m) {
                #pragma unroll
                for (int n = 0; n < 4; ++n) {
                    acc[m][n] = __builtin_amdgcn_mfma_f32_16x16x32_f16(a[m], bhi[n], acc[m][n], 0, 0, 0);
                    acc[m][n] = __builtin_amdgcn_mfma_f32_16x16x32_f16(a[m], blo[n], acc[m][n], 0, 0, 0);
                }
            }
            __builtin_amdgcn_s_setprio(0);
        }
    }

    // ---- epilogue: /4096 (input&weight 2^6 scales), +noise, leaky 0.2 ----
    const float inv = 1.f / 4096.f;
    #pragma unroll
    for (int m = 0; m < 8; ++m) {
        const int coutb = ch*128 + m*16 + kg*4;
        float nwv[4];
        #pragma unroll
        for (int r = 0; r < 4; ++r) nwv[r] = nw[coutb + r];
        #pragma unroll
        for (int n = 0; n < 4; ++n) {
            const int col = n*16 + lcol;
            #pragma unroll
            for (int r = 0; r < 4; ++r) {
                float v = acc[m][n][r]*inv + nwv[r]*nz[n];
                v = fmaxf(v, 0.2f*v);                 // leaky relu 0.2
                const int cout = coutb + r;
                if (MODE == 0) {
                    float vs = v * 64.f;
                    f16 h = (f16)vs;
                    f16 l = (f16)(vs - (float)h);
                    uint32_t pk = (uint32_t)__builtin_bit_cast(uint16_t, h)
                                | ((uint32_t)__builtin_bit_cast(uint16_t, l) << 16);
                    size_t idx = (((size_t)(b*8 + (cout >> 5))*64 + y)*64 + col)*32 + (cout & 31);
                    out_pair[idx] = pk;
                } else {
                    out32[((size_t)(b*256 + cout))*4096 + y*64 + col] = v;
                }
            }
        }
    }
}

// ---------------------------------------------------------------------------
extern "C" void kernel_launch(void* const* d_in, const int* in_sizes, int n_in,
                              void* d_out, int out_size, void* d_ws, size_t ws_size,
                              hipStream_t stream) {
    (void)in_sizes; (void)n_in; (void)out_size; (void)ws_size;
    const float* x      = (const float*)d_in[0];
    const float* w1     = (const float*)d_in[1];
    const float* w2     = (const float*)d_in[2];
    const float* noise1 = (const float*)d_in[3];
    const float* noise2 = (const float*)d_in[4];
    const float* s1w    = (const float*)d_in[5];
    const float* s1b    = (const float*)d_in[6];
    const float* c1w    = (const float*)d_in[7];
    const float* nw1    = (const float*)d_in[8];
    const float* s2w    = (const float*)d_in[9];
    const float* s2b    = (const float*)d_in[10];
    const float* c2w    = (const float*)d_in[11];
    const float* nw2    = (const float*)d_in[12];
    float* out = (float*)d_out;

    f16*      wf    = (f16*)d_ws;
    uint32_t* hpair = (uint32_t*)((char*)d_ws + WF_BYTES);   // 16*8*64*64*32 u32 = 67.1MB

    (void)hipFuncSetAttribute(reinterpret_cast<const void*>(&conv_kernel<0>),
                              hipFuncAttributeMaxDynamicSharedMemorySize, SMEM_TOTAL);
    (void)hipFuncSetAttribute(reinterpret_cast<const void*>(&conv_kernel<1>),
                              hipFuncAttributeMaxDynamicSharedMemorySize, SMEM_TOTAL);

    prep_kernel<<<128, 256, 0, stream>>>(w1, s1w, s1b, c1w, wf);
    conv_kernel<0><<<512, 256, SMEM_TOTAL, stream>>>(x, nullptr, wf, noise1, nw1, nullptr, hpair);
    prep_kernel<<<128, 256, 0, stream>>>(w2, s2w, s2b, c2w, wf);
    conv_kernel<1><<<512, 256, SMEM_TOTAL, stream>>>(nullptr, hpair, wf, noise2, nw2, out, nullptr);
}